// Round 11
// baseline (126.060 us; speedup 1.0000x reference)
//
#include <hip/hip_runtime.h>
#include <cstdint>

constexpr int Bv = 16, Nv = 4096, Fv = 512, Sv = 8, Kv = 1024, Dv = 64;
constexpr int Mv = Bv * Nv;  // 65536 rows
#define BDIM 256
constexpr int RG = 4;        // 16-row groups per wave -> 64 rows/wave, 256/block

using bf16x8 = __attribute__((ext_vector_type(8))) short;
using f32x4  = __attribute__((ext_vector_type(4))) float;
typedef unsigned short u16;
typedef unsigned int u32;

__device__ __forceinline__ u16 bf16rne(float f) {
  union { float f; u32 u; } v; v.f = f;
  u32 u = v.u + 0x7FFFu + ((v.u >> 16) & 1u);
  return (u16)(u >> 16);
}

__device__ __forceinline__ void gload_lds16(const void* g, void* lds) {
  __builtin_amdgcn_global_load_lds(
      (const __attribute__((address_space(1))) void*)g,
      (__attribute__((address_space(3))) void*)lds, 16, 0, 0);
}

// prep: cb fp32 -> swizzled bf16 codebook + c2m = -0.5*sum(c^2) (argmax form)
// swz layout: [s*1024+cw][slot'][8 bf16], slot' = slot ^ (cw&7)
__global__ void prep_kernel(const float* __restrict__ cb, u16* __restrict__ swz,
                            float* __restrict__ c2m) {
  int idx = blockIdx.x * BDIM + threadIdx.x;  // s*1024+cw
  int cw = idx & (Kv - 1);
  const float4* src = (const float4*)(cb + (size_t)idx * Dv);
  float v[64];
  float s2 = 0.f;
#pragma unroll
  for (int i = 0; i < 16; ++i) {
    float4 f = src[i];
    v[i * 4 + 0] = f.x; v[i * 4 + 1] = f.y; v[i * 4 + 2] = f.z; v[i * 4 + 3] = f.w;
    s2 += f.x * f.x + f.y * f.y + f.z * f.z + f.w * f.w;
  }
  c2m[idx] = -0.5f * s2;
  uint4* out = (uint4*)(swz + (size_t)idx * Dv);
#pragma unroll
  for (int slot = 0; slot < 8; ++slot) {
    int slotp = slot ^ (cw & 7);
    u32 w[4];
#pragma unroll
    for (int p = 0; p < 4; ++p)
      w[p] = (u32)bf16rne(v[slot * 8 + p * 2]) | ((u32)bf16rne(v[slot * 8 + p * 2 + 1]) << 16);
    uint4 pk; pk.x = w[0]; pk.y = w[1]; pk.z = w[2]; pk.w = w[3];
    out[slotp] = pk;
  }
}

// main: block = 256 rows x 1 subspace, 4 independent waves, 64 tiles of 16 cw.
// SOFTWARE-PIPELINED phase: stage(t+2)->LDS || ds_read(t+1)->regs || MFMA(t)
// from regs read LAST phase || in-phase argmax. Even/odd static register
// buffers (aE/aO, c2E/c2O). Private 2-slot LDS rings (slot = tile&1), counted
// vmcnt(2), no main-loop barriers. score = <x,c> - 0.5*c2 via
// mfma(A=cb,B=x,C=c2m); lane-local argMAX, 10-bit index in low mantissa bits.
__global__ __launch_bounds__(BDIM, 4) void pq_mfma(
    const float* __restrict__ x, const float* __restrict__ cb,
    const u16* __restrict__ swz, const float* __restrict__ c2m_g,
    float* __restrict__ quant, float* __restrict__ devpart) {
  __shared__ __attribute__((aligned(16))) u16 ring[4][2][16 * Dv];  // 16KB
  __shared__ __attribute__((aligned(16))) float c2_lds[Kv];         // 4KB

  const int tid = threadIdx.x;
  const int s = blockIdx.y;
  const int row0 = blockIdx.x * 256;
  const int wave = tid >> 6, lane = tid & 63;
  const int l15 = lane & 15, lg = lane >> 4;
  const int slotp0 = lg ^ (l15 & 7);        // swizzled 16B-slot, h=0
  const int slotp1 = (4 + lg) ^ (l15 & 7);  // h=1

  const u16* swz_s = swz + (size_t)s * Kv * Dv;
  u16* slot0 = &ring[wave][0][0];
  u16* slot1 = &ring[wave][1][0];

  // per-wave private staging of one 16-cw tile (2 x 1KB)
  auto stage = [&](int t, u16* dst) {
    const u16* src = swz_s + (size_t)t * (16 * Dv) + lane * 8;
    gload_lds16(src, dst);
    gload_lds16(src + 512, dst + 512);
  };

  // ---- prologue: c2 (cooperative) + tiles 0,1; then x->xf
  gload_lds16(c2m_g + s * Kv + tid * 4, &c2_lds[(tid & ~63) * 4]);
  stage(0, slot0); stage(1, slot1);

  bf16x8 xf[RG][2];
  float x2p[RG];
#pragma unroll
  for (int rg = 0; rg < RG; ++rg) {
    x2p[rg] = 0.f;
    const int row = row0 + wave * 64 + rg * 16 + l15;
    const float* xp = x + (size_t)row * Fv + s * Dv + lg * 8;
#pragma unroll
    for (int h = 0; h < 2; ++h) {
      float4 f0 = *(const float4*)(xp + h * 32);
      float4 f1 = *(const float4*)(xp + h * 32 + 4);
      x2p[rg] += f0.x * f0.x + f0.y * f0.y + f0.z * f0.z + f0.w * f0.w
               + f1.x * f1.x + f1.y * f1.y + f1.z * f1.z + f1.w * f1.w;
      bf16x8 v;
      v[0] = (short)bf16rne(f0.x); v[1] = (short)bf16rne(f0.y);
      v[2] = (short)bf16rne(f0.z); v[3] = (short)bf16rne(f0.w);
      v[4] = (short)bf16rne(f1.x); v[5] = (short)bf16rne(f1.y);
      v[6] = (short)bf16rne(f1.z); v[7] = (short)bf16rne(f1.w);
      xf[rg][h] = v;
    }
  }

  float bv[RG];
#pragma unroll
  for (int rg = 0; rg < RG; ++rg) bv[rg] = -3.0e38f;

  // c2 + tile0 landed (tile1's 2 loads may remain); barrier makes c2 global
  asm volatile("s_waitcnt vmcnt(2)" ::: "memory");
  __builtin_amdgcn_s_barrier();

  // hoisted LDS read pointers (swizzled)
  const u16* r0s0 = slot0 + l15 * Dv + slotp0 * 8;
  const u16* r1s0 = slot0 + l15 * Dv + slotp1 * 8;
  const u16* r0s1 = slot1 + l15 * Dv + slotp0 * 8;
  const u16* r1s1 = slot1 + l15 * Dv + slotp1 * 8;

  // even/odd frag + c2 register buffers (static names — rule #20)
  bf16x8 aE0, aE1, aO0, aO1;
  f32x4 c2E, c2O;

  // preload tile 0 -> E
  aE0 = *(const bf16x8*)r0s0;
  aE1 = *(const bf16x8*)r1s0;
  c2E = *(const f32x4*)&c2_lds[lg * 4];

  auto readO = [&](int t1) {  // prefetch odd tile t1 -> O regs
    aO0 = *(const bf16x8*)r0s1;
    aO1 = *(const bf16x8*)r1s1;
    c2O = *(const f32x4*)&c2_lds[t1 * 16 + lg * 4];
  };
  auto readE = [&](int t1) {  // prefetch even tile t1 -> E regs
    aE0 = *(const bf16x8*)r0s0;
    aE1 = *(const bf16x8*)r1s0;
    c2E = *(const f32x4*)&c2_lds[t1 * 16 + lg * 4];
  };
  auto computeE = [&](int t) {  // MFMA tile t from E regs + in-phase argmax
    const u32 kb = (u32)(t * 16) | (u32)(lg * 4);
    __builtin_amdgcn_s_setprio(1);
#pragma unroll
    for (int rg = 0; rg < RG; ++rg) {
      f32x4 acc = __builtin_amdgcn_mfma_f32_16x16x32_bf16(aE0, xf[rg][0], c2E, 0, 0, 0);
      acc = __builtin_amdgcn_mfma_f32_16x16x32_bf16(aE1, xf[rg][1], acc, 0, 0, 0);
      float p0 = __builtin_bit_cast(float, __builtin_bit_cast(u32, acc[0]) | kb);
      float p1 = __builtin_bit_cast(float, __builtin_bit_cast(u32, acc[1]) | (kb | 1u));
      float p2 = __builtin_bit_cast(float, __builtin_bit_cast(u32, acc[2]) | (kb | 2u));
      float p3 = __builtin_bit_cast(float, __builtin_bit_cast(u32, acc[3]) | (kb | 3u));
      bv[rg] = fmaxf(fmaxf(fmaxf(p0, p1), fmaxf(p2, p3)), bv[rg]);
    }
    __builtin_amdgcn_s_setprio(0);
  };
  auto computeO = [&](int t) {
    const u32 kb = (u32)(t * 16) | (u32)(lg * 4);
    __builtin_amdgcn_s_setprio(1);
#pragma unroll
    for (int rg = 0; rg < RG; ++rg) {
      f32x4 acc = __builtin_amdgcn_mfma_f32_16x16x32_bf16(aO0, xf[rg][0], c2O, 0, 0, 0);
      acc = __builtin_amdgcn_mfma_f32_16x16x32_bf16(aO1, xf[rg][1], acc, 0, 0, 0);
      float p0 = __builtin_bit_cast(float, __builtin_bit_cast(u32, acc[0]) | kb);
      float p1 = __builtin_bit_cast(float, __builtin_bit_cast(u32, acc[1]) | (kb | 1u));
      float p2 = __builtin_bit_cast(float, __builtin_bit_cast(u32, acc[2]) | (kb | 2u));
      float p3 = __builtin_bit_cast(float, __builtin_bit_cast(u32, acc[3]) | (kb | 3u));
      bv[rg] = fmaxf(fmaxf(fmaxf(p0, p1), fmaxf(p2, p3)), bv[rg]);
    }
    __builtin_amdgcn_s_setprio(0);
  };

  // ---- main loop: 64 tiles, 2 phases per iter; per phase:
  // stage(t+2) || vmcnt(2) [t+1 landed] || ds_read(t+1)->regs || MFMA(t)+argmax
#pragma unroll 1
  for (int t = 0; t < 60; t += 2) {
    stage(t + 2, slot0);
    asm volatile("s_waitcnt vmcnt(2)" ::: "memory");
    readO(t + 1);
    computeE(t);
    stage(t + 3, slot1);
    asm volatile("s_waitcnt vmcnt(2)" ::: "memory");
    readE(t + 2);
    computeO(t + 1);
  }
  // peeled tail: 60..63
  stage(62, slot0);
  asm volatile("s_waitcnt vmcnt(2)" ::: "memory");
  readO(61); computeE(60);
  stage(63, slot1);
  asm volatile("s_waitcnt vmcnt(2)" ::: "memory");
  readE(62); computeO(61);
  asm volatile("s_waitcnt vmcnt(0)" ::: "memory");
  readO(63); computeE(62);
  computeO(63);

  // ---- cross-lane: max packed scores + sum x2 over the 4 lg groups
#pragma unroll
  for (int rg = 0; rg < RG; ++rg) {
    float b = bv[rg], xx = x2p[rg];
    b = fmaxf(b, __shfl_xor(b, 16, 64)); xx += __shfl_xor(xx, 16, 64);
    b = fmaxf(b, __shfl_xor(b, 32, 64)); xx += __shfl_xor(xx, 32, 64);
    bv[rg] = b; x2p[rg] = xx;
  }

  // dev partial: dist_row = x2 - 2*score_max (packed low bits ~1e-7, negligible)
  float dev = 0.f;
#pragma unroll
  for (int rg = 0; rg < RG; ++rg) dev += x2p[rg] - 2.f * bv[rg];
#pragma unroll
  for (int m = 1; m <= 8; m <<= 1) dev += __shfl_xor(dev, m, 64);
  if (lane == 0)
    devpart[((size_t)blockIdx.y * gridDim.x + blockIdx.x) * 4 + wave] = dev;

  // ---- coalesced quant gather: iter i covers rows i*4+lg; index shfl'd from
  // the lane holding that row; k = low 10 bits of packed max. 16-lane groups
  // write full 256B contiguous segments; nontemporal (write-once).
  const float* cbs = cb + (size_t)s * Kv * Dv;
  float* qbase = quant + (size_t)(row0 + wave * 64) * Fv + s * Dv;
#pragma unroll
  for (int i = 0; i < 16; ++i) {
    int rl = i * 4 + lg;
    int kk = __shfl(__builtin_bit_cast(int, bv[i >> 2]), 4 * (i & 3) + lg, 64) & 1023;
    f32x4 v = *(const f32x4*)(cbs + (size_t)kk * Dv + l15 * 4);
    __builtin_nontemporal_store(v, (f32x4*)(qbase + (size_t)rl * Fv + l15 * 4));
  }
}

// deterministic final reduction of 8192 wave partials -> dev scalar
__global__ void dev_reduce(const float* __restrict__ part, float* __restrict__ out) {
  __shared__ float sred[256];
  int tid = threadIdx.x;
  float s = 0.f;
  for (int i = tid; i < 8192; i += 256) s += part[i];
  sred[tid] = s;
  __syncthreads();
  for (int off = 128; off > 0; off >>= 1) {
    if (tid < off) sred[tid] += sred[tid + off];
    __syncthreads();
  }
  if (tid == 0) out[0] = sred[0] * (1.25f / 4194304.0f);
}

extern "C" void kernel_launch(void* const* d_in, const int* in_sizes, int n_in,
                              void* d_out, int out_size, void* d_ws, size_t ws_size,
                              hipStream_t stream) {
  const float* x = (const float*)d_in[0];   // (B,N,F) fp32
  const float* cb = (const float*)d_in[1];  // (S,K,D) fp32
  float* quant = (float*)d_out;
  float* dev = quant + (size_t)Mv * Fv;

  // ws: swz bf16 codebook (1MB), c2m (32KB), dev partials (32KB)
  u16* swz = (u16*)d_ws;
  float* c2m = (float*)(swz + (size_t)Sv * Kv * Dv);
  float* part = c2m + Sv * Kv;

  prep_kernel<<<(Sv * Kv) / BDIM, BDIM, 0, stream>>>(cb, swz, c2m);
  dim3 grid(Mv / 256, Sv);
  pq_mfma<<<grid, BDIM, 0, stream>>>(x, cb, swz, c2m, quant, part);
  dev_reduce<<<1, 256, 0, stream>>>(part, dev);
}

// Round 12
// 107.222 us; speedup vs baseline: 1.1757x; 1.1757x over previous
//
#include <hip/hip_runtime.h>
#include <cstdint>

constexpr int Bv = 16, Nv = 4096, Fv = 512, Sv = 8, Kv = 1024, Dv = 64;
constexpr int Mv = Bv * Nv;  // 65536 rows
#define BDIM 512
constexpr int RG = 4;        // 16-row groups per wave -> 64 rows/wave/unit

using bf16x8 = __attribute__((ext_vector_type(8))) short;
using f32x4  = __attribute__((ext_vector_type(4))) float;
typedef unsigned short u16;
typedef unsigned int u32;

__device__ __forceinline__ u16 bf16rne(float f) {
  union { float f; u32 u; } v; v.f = f;
  u32 u = v.u + 0x7FFFu + ((v.u >> 16) & 1u);
  return (u16)(u >> 16);
}

__device__ __forceinline__ void gload_lds16(const void* g, void* lds) {
  __builtin_amdgcn_global_load_lds(
      (const __attribute__((address_space(1))) void*)g,
      (__attribute__((address_space(3))) void*)lds, 16, 0, 0);
}
__device__ __forceinline__ void gload_lds4(const void* g, void* lds) {
  __builtin_amdgcn_global_load_lds(
      (const __attribute__((address_space(1))) void*)g,
      (__attribute__((address_space(3))) void*)lds, 4, 0, 0);
}

// prep: cb fp32 -> swizzled bf16 codebook + c2m = -0.5*sum(c^2) (argmax form)
// swz layout: [s*1024+cw][slot'][8 bf16], slot' = slot ^ (cw&7)
__global__ void prep_kernel(const float* __restrict__ cb, u16* __restrict__ swz,
                            float* __restrict__ c2m) {
  int idx = blockIdx.x * 256 + threadIdx.x;  // s*1024+cw
  int cw = idx & (Kv - 1);
  const float4* src = (const float4*)(cb + (size_t)idx * Dv);
  float v[64];
  float s2 = 0.f;
#pragma unroll
  for (int i = 0; i < 16; ++i) {
    float4 f = src[i];
    v[i * 4 + 0] = f.x; v[i * 4 + 1] = f.y; v[i * 4 + 2] = f.z; v[i * 4 + 3] = f.w;
    s2 += f.x * f.x + f.y * f.y + f.z * f.z + f.w * f.w;
  }
  c2m[idx] = -0.5f * s2;
  uint4* out = (uint4*)(swz + (size_t)idx * Dv);
#pragma unroll
  for (int slot = 0; slot < 8; ++slot) {
    int slotp = slot ^ (cw & 7);
    u32 w[4];
#pragma unroll
    for (int p = 0; p < 4; ++p)
      w[p] = (u32)bf16rne(v[slot * 8 + p * 2]) | ((u32)bf16rne(v[slot * 8 + p * 2 + 1]) << 16);
    uint4 pk; pk.x = w[0]; pk.y = w[1]; pk.z = w[2]; pk.w = w[3];
    out[slotp] = pk;
  }
}

// main: block = 8 waves x 1 subspace; the ENTIRE subspace codebook (128KB swz
// bf16 + 4KB c2) is staged into LDS once. Then 2 units of 512 rows: per unit,
// the k-loop over all 64 codeword tiles is pure {ds_read, MFMA, argmax} — no
// vmem, no waits, no barriers. Next unit's x loads are issued before the
// current epilogue (T14). score = <x,c> - 0.5*c2 via mfma(A=cb,B=x,C=c2m);
// lane-local argMAX with the 10-bit index OR'd into the low mantissa bits.
__global__ __launch_bounds__(BDIM, 2) void pq_mfma(
    const float* __restrict__ x, const float* __restrict__ cb,
    const u16* __restrict__ swz, const float* __restrict__ c2m_g,
    float* __restrict__ quant, float* __restrict__ devpart) {
  __shared__ __attribute__((aligned(16))) u16 cw_lds[Kv * Dv];  // 128KB
  __shared__ __attribute__((aligned(16))) float c2_lds[Kv];     // 4KB

  const int tid = threadIdx.x;
  const int s = blockIdx.x & 7;
  const int chunk = blockIdx.x >> 3;      // 64 chunks of 1024 rows per subspace
  const int wave = tid >> 6, lane = tid & 63;
  const int l15 = lane & 15, lg = lane >> 4;
  const int slotp0 = lg ^ (l15 & 7);       // swizzled 16B-slot, h=0
  const int slotp1 = (4 + lg) ^ (l15 & 7); // h=1

  // ---- stage the whole subspace codebook once (16 x 8KB) + c2 (2 x 2KB)
  const u16* swz_s = swz + (size_t)s * Kv * Dv;
#pragma unroll
  for (int it = 0; it < 16; ++it)
    gload_lds16(swz_s + (size_t)(it * BDIM + tid) * 8,
                &cw_lds[(it * BDIM + (tid & ~63)) * 8]);
#pragma unroll
  for (int it = 0; it < 2; ++it)
    gload_lds4(c2m_g + s * Kv + it * BDIM + tid,
               &c2_lds[it * BDIM + (tid & ~63)]);

  // ---- unit-0 x loads (after staging issue; consumed post-barrier)
  float4 xr[2 * RG];
  const float* xbase0 = x + (size_t)(chunk * 1024 + wave * 64) * Fv + s * Dv;
#pragma unroll
  for (int rg = 0; rg < RG; ++rg) {
    const float* xp = xbase0 + (size_t)(rg * 16 + l15) * Fv + lg * 8;
    xr[rg * 2] = *(const float4*)xp;
    xr[rg * 2 + 1] = *(const float4*)(xp + 4);
  }

  __syncthreads();  // full drain: codebook + c2 staged, visible to all waves

  // lane-fixed LDS read pointers; tile t adds t*16*Dv
  const u16* r0 = cw_lds + l15 * Dv + slotp0 * 8;
  const u16* r1 = cw_lds + l15 * Dv + slotp1 * 8;

  float devacc = 0.f;

#pragma unroll 1
  for (int u = 0; u < 2; ++u) {
    const int rowu = chunk * 1024 + u * 512 + wave * 64;

    // ---- cvt xr -> xf fragments + x2 partials
    bf16x8 xf[RG][2];
    float x2p[RG];
#pragma unroll
    for (int rg = 0; rg < RG; ++rg) {
      float4 f0 = xr[rg * 2], f1 = xr[rg * 2 + 1];
      x2p[rg] = f0.x * f0.x + f0.y * f0.y + f0.z * f0.z + f0.w * f0.w
              + f1.x * f1.x + f1.y * f1.y + f1.z * f1.z + f1.w * f1.w;
      bf16x8 v;
      v[0] = (short)bf16rne(f0.x); v[1] = (short)bf16rne(f0.y);
      v[2] = (short)bf16rne(f0.z); v[3] = (short)bf16rne(f0.w);
      v[4] = (short)bf16rne(f1.x); v[5] = (short)bf16rne(f1.y);
      v[6] = (short)bf16rne(f1.z); v[7] = (short)bf16rne(f1.w);
      xf[rg][0] = v;
      // second half (d = 32..63) comes from the h=1 slot pair
      const float* xp = x + (size_t)(rowu + rg * 16 + l15) * Fv + s * Dv + 32 + lg * 8;
      float4 g0 = *(const float4*)xp;
      float4 g1 = *(const float4*)(xp + 4);
      x2p[rg] += g0.x * g0.x + g0.y * g0.y + g0.z * g0.z + g0.w * g0.w
               + g1.x * g1.x + g1.y * g1.y + g1.z * g1.z + g1.w * g1.w;
      bf16x8 w;
      w[0] = (short)bf16rne(g0.x); w[1] = (short)bf16rne(g0.y);
      w[2] = (short)bf16rne(g0.z); w[3] = (short)bf16rne(g0.w);
      w[4] = (short)bf16rne(g1.x); w[5] = (short)bf16rne(g1.y);
      w[6] = (short)bf16rne(g1.z); w[7] = (short)bf16rne(g1.w);
      xf[rg][1] = w;
    }

    float bv[RG];
#pragma unroll
    for (int rg = 0; rg < RG; ++rg) bv[rg] = -3.0e38f;

    // even/odd register double-buffer for codebook fragments
    bf16x8 aE0, aE1, aO0, aO1;
    f32x4 c2E, c2O;
    aE0 = *(const bf16x8*)r0;
    aE1 = *(const bf16x8*)r1;
    c2E = *(const f32x4*)&c2_lds[lg * 4];

    auto readO = [&](int t1) {
      aO0 = *(const bf16x8*)(r0 + t1 * 16 * Dv);
      aO1 = *(const bf16x8*)(r1 + t1 * 16 * Dv);
      c2O = *(const f32x4*)&c2_lds[t1 * 16 + lg * 4];
    };
    auto readE = [&](int t1) {
      aE0 = *(const bf16x8*)(r0 + t1 * 16 * Dv);
      aE1 = *(const bf16x8*)(r1 + t1 * 16 * Dv);
      c2E = *(const f32x4*)&c2_lds[t1 * 16 + lg * 4];
    };
    auto computeE = [&](int t) {
      const u32 kb = (u32)(t * 16) | (u32)(lg * 4);
      __builtin_amdgcn_s_setprio(1);
#pragma unroll
      for (int rg = 0; rg < RG; ++rg) {
        f32x4 acc = __builtin_amdgcn_mfma_f32_16x16x32_bf16(aE0, xf[rg][0], c2E, 0, 0, 0);
        acc = __builtin_amdgcn_mfma_f32_16x16x32_bf16(aE1, xf[rg][1], acc, 0, 0, 0);
        float p0 = __builtin_bit_cast(float, __builtin_bit_cast(u32, acc[0]) | kb);
        float p1 = __builtin_bit_cast(float, __builtin_bit_cast(u32, acc[1]) | (kb | 1u));
        float p2 = __builtin_bit_cast(float, __builtin_bit_cast(u32, acc[2]) | (kb | 2u));
        float p3 = __builtin_bit_cast(float, __builtin_bit_cast(u32, acc[3]) | (kb | 3u));
        bv[rg] = fmaxf(fmaxf(fmaxf(p0, p1), fmaxf(p2, p3)), bv[rg]);
      }
      __builtin_amdgcn_s_setprio(0);
    };
    auto computeO = [&](int t) {
      const u32 kb = (u32)(t * 16) | (u32)(lg * 4);
      __builtin_amdgcn_s_setprio(1);
#pragma unroll
      for (int rg = 0; rg < RG; ++rg) {
        f32x4 acc = __builtin_amdgcn_mfma_f32_16x16x32_bf16(aO0, xf[rg][0], c2O, 0, 0, 0);
        acc = __builtin_amdgcn_mfma_f32_16x16x32_bf16(aO1, xf[rg][1], acc, 0, 0, 0);
        float p0 = __builtin_bit_cast(float, __builtin_bit_cast(u32, acc[0]) | kb);
        float p1 = __builtin_bit_cast(float, __builtin_bit_cast(u32, acc[1]) | (kb | 1u));
        float p2 = __builtin_bit_cast(float, __builtin_bit_cast(u32, acc[2]) | (kb | 2u));
        float p3 = __builtin_bit_cast(float, __builtin_bit_cast(u32, acc[3]) | (kb | 3u));
        bv[rg] = fmaxf(fmaxf(fmaxf(p0, p1), fmaxf(p2, p3)), bv[rg]);
      }
      __builtin_amdgcn_s_setprio(0);
    };

    // ---- k-loop: 64 tiles, pure LDS + MFMA + VALU; no vmem, no barriers
#pragma unroll 1
    for (int t = 0; t < 62; t += 2) {
      readO(t + 1);
      computeE(t);
      readE(t + 2);
      computeO(t + 1);
    }
    readO(63);
    computeE(62);
    computeO(63);

    // ---- cross-lane: max packed scores + sum x2 over the 4 lg groups
#pragma unroll
    for (int rg = 0; rg < RG; ++rg) {
      float b = bv[rg], xx = x2p[rg];
      b = fmaxf(b, __shfl_xor(b, 16, 64)); xx += __shfl_xor(xx, 16, 64);
      b = fmaxf(b, __shfl_xor(b, 32, 64)); xx += __shfl_xor(xx, 32, 64);
      bv[rg] = b; x2p[rg] = xx;
    }
#pragma unroll
    for (int rg = 0; rg < RG; ++rg) devacc += x2p[rg] - 2.f * bv[rg];

    // ---- issue next unit's x loads BEFORE the epilogue (latency hides under it)
    if (u == 0) {
      const float* xb = x + (size_t)(chunk * 1024 + 512 + wave * 64) * Fv + s * Dv;
#pragma unroll
      for (int rg = 0; rg < RG; ++rg) {
        const float* xp = xb + (size_t)(rg * 16 + l15) * Fv + lg * 8;
        xr[rg * 2] = *(const float4*)xp;
        xr[rg * 2 + 1] = *(const float4*)(xp + 4);
      }
    }

    // ---- coalesced quant gather/write for this unit
    const float* cbs = cb + (size_t)s * Kv * Dv;
    float* qbase = quant + (size_t)rowu * Fv + s * Dv;
#pragma unroll
    for (int i = 0; i < 16; ++i) {
      int rl = i * 4 + lg;
      int kk = __shfl(__builtin_bit_cast(int, bv[i >> 2]), 4 * (i & 3) + lg, 64) & 1023;
      f32x4 v = *(const f32x4*)(cbs + (size_t)kk * Dv + l15 * 4);
      __builtin_nontemporal_store(v, (f32x4*)(qbase + (size_t)rl * Fv + l15 * 4));
    }
  }

  // ---- dev partial per wave
#pragma unroll
  for (int m = 1; m <= 8; m <<= 1) devacc += __shfl_xor(devacc, m, 64);
  if (lane == 0) devpart[(size_t)blockIdx.x * 8 + wave] = devacc;
}

// deterministic final reduction of 4096 wave partials -> dev scalar
__global__ void dev_reduce(const float* __restrict__ part, float* __restrict__ out) {
  __shared__ float sred[256];
  int tid = threadIdx.x;
  float s = 0.f;
  for (int i = tid; i < 4096; i += 256) s += part[i];
  sred[tid] = s;
  __syncthreads();
  for (int off = 128; off > 0; off >>= 1) {
    if (tid < off) sred[tid] += sred[tid + off];
    __syncthreads();
  }
  if (tid == 0) out[0] = sred[0] * (1.25f / 4194304.0f);
}

extern "C" void kernel_launch(void* const* d_in, const int* in_sizes, int n_in,
                              void* d_out, int out_size, void* d_ws, size_t ws_size,
                              hipStream_t stream) {
  const float* x = (const float*)d_in[0];   // (B,N,F) fp32
  const float* cb = (const float*)d_in[1];  // (S,K,D) fp32
  float* quant = (float*)d_out;
  float* dev = quant + (size_t)Mv * Fv;

  // ws: swz bf16 codebook (1MB), c2m (32KB), dev partials (16KB)
  u16* swz = (u16*)d_ws;
  float* c2m = (float*)(swz + (size_t)Sv * Kv * Dv);
  float* part = c2m + Sv * Kv;

  prep_kernel<<<(Sv * Kv) / 256, 256, 0, stream>>>(cb, swz, c2m);
  pq_mfma<<<512, BDIM, 0, stream>>>(x, cb, swz, c2m, quant, part);
  dev_reduce<<<1, 256, 0, stream>>>(part, dev);
}

// Round 13
// 104.660 us; speedup vs baseline: 1.2045x; 1.0245x over previous
//
#include <hip/hip_runtime.h>
#include <cstdint>

constexpr int Bv = 16, Nv = 4096, Fv = 512, Sv = 8, Kv = 1024, Dv = 64;
constexpr int Mv = Bv * Nv;  // 65536 rows
#define BDIM 512
constexpr int RG = 4;        // 16-row groups per wave -> 64 rows/wave/unit

using bf16x8 = __attribute__((ext_vector_type(8))) short;
using f32x4  = __attribute__((ext_vector_type(4))) float;
typedef unsigned short u16;
typedef unsigned int u32;

__device__ __forceinline__ u16 bf16rne(float f) {
  union { float f; u32 u; } v; v.f = f;
  u32 u = v.u + 0x7FFFu + ((v.u >> 16) & 1u);
  return (u16)(u >> 16);
}

__device__ __forceinline__ u32 cvtpk(float lo, float hi) {
  u32 r;
  asm("v_cvt_pk_bf16_f32 %0, %1, %2" : "=v"(r) : "v"(lo), "v"(hi));
  return r;
}

__device__ __forceinline__ void gload_lds16(const void* g, void* lds) {
  __builtin_amdgcn_global_load_lds(
      (const __attribute__((address_space(1))) void*)g,
      (__attribute__((address_space(3))) void*)lds, 16, 0, 0);
}
__device__ __forceinline__ void gload_lds4(const void* g, void* lds) {
  __builtin_amdgcn_global_load_lds(
      (const __attribute__((address_space(1))) void*)g,
      (__attribute__((address_space(3))) void*)lds, 4, 0, 0);
}

// prep: cb fp32 -> swizzled bf16 codebook + c2m = -0.5*sum(c^2) (argmax form)
// swz layout: [s*1024+cw][slot'][8 bf16], slot' = slot ^ (cw&7)
__global__ void prep_kernel(const float* __restrict__ cb, u16* __restrict__ swz,
                            float* __restrict__ c2m) {
  int idx = blockIdx.x * 256 + threadIdx.x;  // s*1024+cw
  int cw = idx & (Kv - 1);
  const float4* src = (const float4*)(cb + (size_t)idx * Dv);
  float v[64];
  float s2 = 0.f;
#pragma unroll
  for (int i = 0; i < 16; ++i) {
    float4 f = src[i];
    v[i * 4 + 0] = f.x; v[i * 4 + 1] = f.y; v[i * 4 + 2] = f.z; v[i * 4 + 3] = f.w;
    s2 += f.x * f.x + f.y * f.y + f.z * f.z + f.w * f.w;
  }
  c2m[idx] = -0.5f * s2;
  uint4* out = (uint4*)(swz + (size_t)idx * Dv);
#pragma unroll
  for (int slot = 0; slot < 8; ++slot) {
    int slotp = slot ^ (cw & 7);
    u32 w[4];
#pragma unroll
    for (int p = 0; p < 4; ++p)
      w[p] = (u32)bf16rne(v[slot * 8 + p * 2]) | ((u32)bf16rne(v[slot * 8 + p * 2 + 1]) << 16);
    uint4 pk; pk.x = w[0]; pk.y = w[1]; pk.z = w[2]; pk.w = w[3];
    out[slotp] = pk;
  }
}

// main: block = 8 waves x 1 subspace; whole subspace codebook (128KB swz bf16 +
// 4KB c2) LDS-resident. 2 units of 512 rows. k-loop is a DEFERRED-ARGMAX
// software pipeline: issue tile t's MFMA cluster, then argmax tile t-1's accs
// (static accE/accO buffers) — MFMA latency hidden under the previous tile's
// VALU. No vmem, no barriers in the k-loop. score = <x,c> - 0.5*c2 via
// mfma(A=cb,B=x,C=c2m); lane-local argMAX, 10-bit index in low mantissa bits.
__global__ __launch_bounds__(BDIM, 2) void pq_mfma(
    const float* __restrict__ x, const float* __restrict__ cb,
    const u16* __restrict__ swz, const float* __restrict__ c2m_g,
    float* __restrict__ quant, float* __restrict__ devpart) {
  __shared__ __attribute__((aligned(16))) u16 cw_lds[Kv * Dv];  // 128KB
  __shared__ __attribute__((aligned(16))) float c2_lds[Kv];     // 4KB

  const int tid = threadIdx.x;
  const int s = blockIdx.x & 7;
  const int chunk = blockIdx.x >> 3;      // 64 chunks of 1024 rows per subspace
  const int wave = tid >> 6, lane = tid & 63;
  const int l15 = lane & 15, lg = lane >> 4;
  const int slotp0 = lg ^ (l15 & 7);       // swizzled 16B-slot, h=0 (d 0..31)
  const int slotp1 = (4 + lg) ^ (l15 & 7); // h=1 (d 32..63)

  // ---- stage the whole subspace codebook once (16 x 8KB) + c2 (2 x 2KB)
  const u16* swz_s = swz + (size_t)s * Kv * Dv;
#pragma unroll
  for (int it = 0; it < 16; ++it)
    gload_lds16(swz_s + (size_t)(it * BDIM + tid) * 8,
                &cw_lds[(it * BDIM + (tid & ~63)) * 8]);
#pragma unroll
  for (int it = 0; it < 2; ++it)
    gload_lds4(c2m_g + s * Kv + it * BDIM + tid,
               &c2_lds[it * BDIM + (tid & ~63)]);

  // ---- unit-0 x prefetch (full 64 floats/lane-slice: 4 float4 per rg)
  float4 xr[RG][4];
  {
    const float* xb = x + (size_t)(chunk * 1024 + wave * 64) * Fv + s * Dv;
#pragma unroll
    for (int rg = 0; rg < RG; ++rg) {
      const float* xp = xb + (size_t)(rg * 16 + l15) * Fv + lg * 8;
      xr[rg][0] = *(const float4*)xp;
      xr[rg][1] = *(const float4*)(xp + 4);
      xr[rg][2] = *(const float4*)(xp + 32);
      xr[rg][3] = *(const float4*)(xp + 36);
    }
  }

  __syncthreads();  // codebook + c2 staged and visible

  // lane-fixed LDS read pointers; tile t adds t*16*Dv elements
  const u16* r0 = cw_lds + l15 * Dv + slotp0 * 8;
  const u16* r1 = cw_lds + l15 * Dv + slotp1 * 8;

  const u32 lgr0 = (u32)(lg * 4), lgr1 = lgr0 | 1u, lgr2 = lgr0 | 2u, lgr3 = lgr0 | 3u;
  float devx2 = 0.f, bvsum = 0.f;

#pragma unroll 1
  for (int u = 0; u < 2; ++u) {
    const int rowu = chunk * 1024 + u * 512 + wave * 64;

    // ---- xr -> bf16 fragments (cvt_pk) + lane-local x2 accumulation
    bf16x8 xf[RG][2];
#pragma unroll
    for (int rg = 0; rg < RG; ++rg) {
#pragma unroll
      for (int h = 0; h < 2; ++h) {
        float4 f0 = xr[rg][h * 2], f1 = xr[rg][h * 2 + 1];
        devx2 += f0.x * f0.x + f0.y * f0.y + f0.z * f0.z + f0.w * f0.w
               + f1.x * f1.x + f1.y * f1.y + f1.z * f1.z + f1.w * f1.w;
        union { u32 w[4]; bf16x8 v; } cvt;
        cvt.w[0] = cvtpk(f0.x, f0.y);
        cvt.w[1] = cvtpk(f0.z, f0.w);
        cvt.w[2] = cvtpk(f1.x, f1.y);
        cvt.w[3] = cvtpk(f1.z, f1.w);
        xf[rg][h] = cvt.v;
      }
    }

    float bv[RG];
#pragma unroll
    for (int rg = 0; rg < RG; ++rg) bv[rg] = -3.0e38f;

    // static even/odd codebook-fragment + accumulator buffers
    bf16x8 aE0, aE1, aO0, aO1;
    f32x4 c2E, c2O;
    f32x4 accE[RG], accO[RG];

    auto readE = [&](int t) {
      aE0 = *(const bf16x8*)(r0 + t * 16 * Dv);
      aE1 = *(const bf16x8*)(r1 + t * 16 * Dv);
      c2E = *(const f32x4*)&c2_lds[t * 16 + lg * 4];
    };
    auto readO = [&](int t) {
      aO0 = *(const bf16x8*)(r0 + t * 16 * Dv);
      aO1 = *(const bf16x8*)(r1 + t * 16 * Dv);
      c2O = *(const f32x4*)&c2_lds[t * 16 + lg * 4];
    };
    auto mfmaE = [&]() {
      __builtin_amdgcn_s_setprio(1);
#pragma unroll
      for (int rg = 0; rg < RG; ++rg)
        accE[rg] = __builtin_amdgcn_mfma_f32_16x16x32_bf16(aE0, xf[rg][0], c2E, 0, 0, 0);
#pragma unroll
      for (int rg = 0; rg < RG; ++rg)
        accE[rg] = __builtin_amdgcn_mfma_f32_16x16x32_bf16(aE1, xf[rg][1], accE[rg], 0, 0, 0);
      __builtin_amdgcn_s_setprio(0);
    };
    auto mfmaO = [&]() {
      __builtin_amdgcn_s_setprio(1);
#pragma unroll
      for (int rg = 0; rg < RG; ++rg)
        accO[rg] = __builtin_amdgcn_mfma_f32_16x16x32_bf16(aO0, xf[rg][0], c2O, 0, 0, 0);
#pragma unroll
      for (int rg = 0; rg < RG; ++rg)
        accO[rg] = __builtin_amdgcn_mfma_f32_16x16x32_bf16(aO1, xf[rg][1], accO[rg], 0, 0, 0);
      __builtin_amdgcn_s_setprio(0);
    };
    auto procE = [&](int tp) {  // argmax tile tp from accE
      const u32 tb = (u32)(tp << 4);
#pragma unroll
      for (int rg = 0; rg < RG; ++rg) {
        float p0 = __builtin_bit_cast(float, (__builtin_bit_cast(u32, accE[rg][0]) | tb) | lgr0);
        float p1 = __builtin_bit_cast(float, (__builtin_bit_cast(u32, accE[rg][1]) | tb) | lgr1);
        float p2 = __builtin_bit_cast(float, (__builtin_bit_cast(u32, accE[rg][2]) | tb) | lgr2);
        float p3 = __builtin_bit_cast(float, (__builtin_bit_cast(u32, accE[rg][3]) | tb) | lgr3);
        float m = fmaxf(fmaxf(p0, p1), p2);
        bv[rg] = fmaxf(fmaxf(m, p3), bv[rg]);
      }
    };
    auto procO = [&](int tp) {
      const u32 tb = (u32)(tp << 4);
#pragma unroll
      for (int rg = 0; rg < RG; ++rg) {
        float p0 = __builtin_bit_cast(float, (__builtin_bit_cast(u32, accO[rg][0]) | tb) | lgr0);
        float p1 = __builtin_bit_cast(float, (__builtin_bit_cast(u32, accO[rg][1]) | tb) | lgr1);
        float p2 = __builtin_bit_cast(float, (__builtin_bit_cast(u32, accO[rg][2]) | tb) | lgr2);
        float p3 = __builtin_bit_cast(float, (__builtin_bit_cast(u32, accO[rg][3]) | tb) | lgr3);
        float m = fmaxf(fmaxf(p0, p1), p2);
        bv[rg] = fmaxf(fmaxf(m, p3), bv[rg]);
      }
    };

    // ---- pipelined k-loop: issue MFMA(t), argmax-process t-1
    readE(0);
    mfmaE();
#pragma unroll 1
    for (int t = 1; t < 63; t += 2) {
      readO(t);
      mfmaO();
      procE(t - 1);
      readE(t + 1);
      mfmaE();
      procO(t);
    }
    readO(63);
    mfmaO();
    procE(62);
    procO(63);

    // ---- cross-lane max over the 4 lg groups (rows preserved in l15)
#pragma unroll
    for (int rg = 0; rg < RG; ++rg) {
      float b = bv[rg];
      b = fmaxf(b, __shfl_xor(b, 16, 64));
      b = fmaxf(b, __shfl_xor(b, 32, 64));
      bv[rg] = b;
      bvsum += b;
    }

    // ---- issue next unit's x loads BEFORE the epilogue (hide under it)
    if (u == 0) {
      const float* xb = x + (size_t)(chunk * 1024 + 512 + wave * 64) * Fv + s * Dv;
#pragma unroll
      for (int rg = 0; rg < RG; ++rg) {
        const float* xp = xb + (size_t)(rg * 16 + l15) * Fv + lg * 8;
        xr[rg][0] = *(const float4*)xp;
        xr[rg][1] = *(const float4*)(xp + 4);
        xr[rg][2] = *(const float4*)(xp + 32);
        xr[rg][3] = *(const float4*)(xp + 36);
      }
    }

    // ---- coalesced quant gather/write for this unit: iter i covers rows
    // i*4+lg; index shfl'd from the lane holding that row; k = low 10 bits.
    const float* cbs = cb + (size_t)s * Kv * Dv;
    float* qbase = quant + (size_t)rowu * Fv + s * Dv;
#pragma unroll
    for (int i = 0; i < 16; ++i) {
      int rl = i * 4 + lg;
      int kk = __shfl(__builtin_bit_cast(int, bv[i >> 2]), 4 * (i & 3) + lg, 64) & 1023;
      f32x4 v = *(const f32x4*)(cbs + (size_t)kk * Dv + l15 * 4);
      __builtin_nontemporal_store(v, (f32x4*)(qbase + (size_t)rl * Fv + l15 * 4));
    }
  }

  // ---- dev partial: sum x2 over all 64 lanes; sum bv over the 16 l15 rows
  // (bv identical across lg after the max-reduce, so reduce masks 1..8 only)
#pragma unroll
  for (int m = 1; m <= 32; m <<= 1) devx2 += __shfl_xor(devx2, m, 64);
#pragma unroll
  for (int m = 1; m <= 8; m <<= 1) bvsum += __shfl_xor(bvsum, m, 64);
  if (lane == 0)
    devpart[(size_t)blockIdx.x * 8 + wave] = devx2 - 2.f * bvsum;
}

// deterministic final reduction of 4096 wave partials -> dev scalar
__global__ void dev_reduce(const float* __restrict__ part, float* __restrict__ out) {
  __shared__ float sred[256];
  int tid = threadIdx.x;
  float s = 0.f;
  for (int i = tid; i < 4096; i += 256) s += part[i];
  sred[tid] = s;
  __syncthreads();
  for (int off = 128; off > 0; off >>= 1) {
    if (tid < off) sred[tid] += sred[tid + off];
    __syncthreads();
  }
  if (tid == 0) out[0] = sred[0] * (1.25f / 4194304.0f);
}

extern "C" void kernel_launch(void* const* d_in, const int* in_sizes, int n_in,
                              void* d_out, int out_size, void* d_ws, size_t ws_size,
                              hipStream_t stream) {
  const float* x = (const float*)d_in[0];   // (B,N,F) fp32
  const float* cb = (const float*)d_in[1];  // (S,K,D) fp32
  float* quant = (float*)d_out;
  float* dev = quant + (size_t)Mv * Fv;

  // ws: swz bf16 codebook (1MB), c2m (32KB), dev partials (16KB)
  u16* swz = (u16*)d_ws;
  float* c2m = (float*)(swz + (size_t)Sv * Kv * Dv);
  float* part = c2m + Sv * Kv;

  prep_kernel<<<(Sv * Kv) / 256, 256, 0, stream>>>(cb, swz, c2m);
  pq_mfma<<<512, BDIM, 0, stream>>>(x, cb, swz, c2m, quant, part);
  dev_reduce<<<1, 256, 0, stream>>>(part, dev);
}